// Round 1
// baseline (593.736 us; speedup 1.0000x reference)
//
#include <hip/hip_runtime.h>

typedef short short8 __attribute__((ext_vector_type(8)));
typedef __bf16 bf16x8 __attribute__((ext_vector_type(8)));
typedef float f32x4 __attribute__((ext_vector_type(4)));

#define HP 258  // padded spatial dim

__device__ __forceinline__ short f2bf(float f) {
  // round-to-nearest-even fp32 -> bf16 (inputs are finite)
  unsigned u = __builtin_bit_cast(unsigned, f);
  unsigned r = u + 0x7fffu + ((u >> 16) & 1u);
  return (short)(r >> 16);
}

__device__ __forceinline__ void async16(void* l, const void* g) {
  __builtin_amdgcn_global_load_lds((const __attribute__((address_space(1))) void*)g,
                                   (__attribute__((address_space(3))) void*)l,
                                   16, 0, 0);
}

// ---------------- fused prepass: all four independent prep jobs in ONE launch ---
// blocks [0,4096): transpose_x   (NCHW fp32 -> padded NHWC bf16)
// blocks [4096,4482): zero_border
// blocks [4482,4644): repack_w
// blocks [4644,5668): valid_mask
__global__ __launch_bounds__(256) void prepass(const float* __restrict__ x,
                                               const int* __restrict__ mask,
                                               const float* __restrict__ Wsrc,
                                               short* __restrict__ Xp,
                                               short* __restrict__ Wr,
                                               float* __restrict__ Vg) {
  __shared__ short lds[64 * 200];  // used by transpose blocks only
  const int t = threadIdx.x;
  const int bid = blockIdx.x;

  if (bid < 4096) {
    // ---- transpose_x: 64-w tile of one (b, ih) row ----
    const int w = t & 63;
    const int g = t >> 6;
    const int w0 = (bid & 3) << 6;
    const int ih = (bid >> 2) & 255;
    const int b = bid >> 10;
    const float* xb = x + ((size_t)b * 192) * 65536 + (size_t)ih * 256 + w0;
#pragma unroll
    for (int pass = 0; pass < 6; ++pass) {
      int ci = pass * 32 + g * 8;
      short8 v;
#pragma unroll
      for (int j = 0; j < 8; ++j) v[j] = f2bf(xb[(size_t)(ci + j) * 65536 + w]);
      *(short8*)&lds[w * 200 + ci] = v;
    }
    __syncthreads();
    short* dst = Xp + (((size_t)b * HP + (ih + 1)) * HP + (w0 + 1)) * 192;
#pragma unroll
    for (int i = 0; i < 6; ++i) {
      int gid = i * 256 + t;  // 1536 granules = 64 w * 24
      int ww = gid / 24;
      int c = gid - ww * 24;
      short8 vv = *(const short8*)&lds[ww * 200 + c * 8];
      *(short8*)&dst[(size_t)ww * 192 + c * 8] = vv;
    }
    return;
  }

  int rb = bid - 4096;
  if (rb < 386) {
    // ---- zero_border ----
    int gid = rb * 256 + t;
    if (gid >= 4 * 1028 * 24) return;
    int g = gid % 24;
    int pix = gid / 24;
    int b = pix / 1028;
    int i = pix - b * 1028;
    int h, w;
    if (i < 258)      { h = 0;   w = i; }
    else if (i < 516) { h = 257; w = i - 258; }
    else { int j = i - 516; h = 1 + (j >> 1); w = (j & 1) ? 257 : 0; }
    short8 z = {0, 0, 0, 0, 0, 0, 0, 0};
    *(short8*)&Xp[(((size_t)b * HP + h) * HP + w) * 192 + g * 8] = z;
    return;
  }
  rb -= 386;
  if (rb < 162) {
    // ---- repack_w: OIHW fp32 -> [tap][kc][swizzled granule] bf16 ----
    int gid = rb * 256 + t;
    if (gid >= 9 * 6 * 768) return;
    int gr = gid % 768;
    int tk = gid / 768;
    int kc = tk % 6;
    int tap = tk / 6;
    int co = gr >> 2;
    int q = (gr & 3) ^ (co & 3);  // XOR swizzle so frag ds_read_b128 is conflict-free
    int ci = kc * 32 + q * 8;
    short8 v;
#pragma unroll
    for (int j = 0; j < 8; ++j) v[j] = f2bf(Wsrc[(size_t)(co * 192 + ci + j) * 9 + tap]);
    *(short8*)&Wr[(size_t)gid * 8] = v;
    return;
  }
  rb -= 162;
  {
    // ---- valid_mask = any(mask 3x3 window) ----
    int gid = rb * 256 + t;  // 262144 exact
    int b = gid >> 16;
    int r = gid & 65535;
    int oh = r >> 8;
    int ow = r & 255;
    const int* mb = mask + ((size_t)b << 16);
    int any = 0;
    for (int dh = -1; dh <= 1; ++dh) {
      int h = oh + dh;
      if ((unsigned)h >= 256u) continue;
      for (int dw = -1; dw <= 1; ++dw) {
        int w = ow + dw;
        if ((unsigned)w >= 256u) continue;
        any |= (mb[h * 256 + w] != 0);
      }
    }
    Vg[gid] = any ? 1.0f : 0.0f;
  }
}

// ---------------- main: implicit-GEMM conv, bf16 MFMA 16x16x32 ----------------
// WG tile: 192 cout x 128 ow (one output row segment). 4 waves: wave w -> cout [48w,48w+48).
// 2-phase pipeline: double-buffered LDS, stage(t+1) issued BEFORE compute(t),
// single __syncthreads() per step (its implicit vmcnt(0) drain lands AFTER the
// MFMA cluster, so global-load latency hides under compute).
__global__ __launch_bounds__(256) void conv_mfma(
    const short* __restrict__ Xp,   // [4][258][258][192] bf16 padded NHWC
    const short* __restrict__ Wr,   // [9][6][768 granules][8] bf16 swizzled
    const float* __restrict__ Vg,   // [4][256][256]
    const float* __restrict__ bias, // [192]
    float* __restrict__ out)        // [4][192][256][256]
{
  __shared__ short Al[2][768 * 8];  // 2 x 12 KB: A chunk, 192 co x 32 ci
  __shared__ short Bl[2][512 * 8];  // 2 x 8 KB:  B chunk, 128 p x 32 ci

  const int t = threadIdx.x;
  const int lane = t & 63;
  const int wave = t >> 6;
  const int quad = lane >> 4;
  const int l16 = lane & 15;

  const int b = blockIdx.z;
  const int by = blockIdx.y;
  // XCD banding: blocks with by%4==c map to XCD pair {2c,2c+1}; give that pair
  // the contiguous oh band [64c,64c+64) so consecutive rows (sharing 2/3 input
  // rows) hit the same L2.
  const int oh = ((by & 3) << 6) | (by >> 2);
  const int ow0 = blockIdx.x << 7;

  // LDS frag read offsets (shorts), loop-invariant. XOR matches staging swizzle.
  const int axor = quad ^ (l16 & 3);
  int aoff[3];
#pragma unroll
  for (int c = 0; c < 3; ++c) aoff[c] = ((wave * 48 + c * 16 + l16) * 4 + axor) * 8;
  int boff[8];
#pragma unroll
  for (int s = 0; s < 8; ++s) boff[s] = ((s * 16 + l16) * 4 + axor) * 8;

  // B staging decode: thread t copies granules t and t+256 (pixels p0 and p0+64).
  const int p0 = t >> 2;
  const int q0 = (t & 3) ^ (p0 & 3);
  const int poff = p0 * 192 + q0 * 8;

  const f32x4 fzero = {0.f, 0.f, 0.f, 0.f};
  f32x4 acc[3][8];
#pragma unroll
  for (int c = 0; c < 3; ++c)
#pragma unroll
    for (int s = 0; s < 8; ++s) acc[c][s] = fzero;

  const short* Xb = Xp + (size_t)b * HP * HP * 192;

  auto stage = [&](int bs, int kh, int kw, int kc) {
    const short* wsrc = Wr + ((size_t)(kh * 3 + kw) * 6 + kc) * (768 * 8) + t * 8;
    async16(&Al[bs][t * 8], wsrc);
    async16(&Al[bs][(t + 256) * 8], wsrc + 256 * 8);
    async16(&Al[bs][(t + 512) * 8], wsrc + 512 * 8);
    const short* xsrc = Xb + ((size_t)(oh + kh) * HP + (ow0 + kw)) * 192 + poff + kc * 32;
    async16(&Bl[bs][t * 8], xsrc);
    async16(&Bl[bs][(t + 256) * 8], xsrc + 64 * 192);
  };

  // prologue: fill buffer 0 (step 0 = tap(0,0), kc 0)
  stage(0, 0, 0, 0);
  __syncthreads();  // vmcnt(0) drain + barrier

  int cur = 0;
  for (int s = 0; s < 54; ++s) {  // step = tap*6 + kc, same order as before
    const int sn = s + 1;
    if (sn < 54) {  // issue next step's loads into the other buffer FIRST
      const int tap = sn / 6;
      const int kc = sn - tap * 6;
      const int kh = tap / 3;
      const int kw = tap - kh * 3;
      stage(cur ^ 1, kh, kw, kc);
    }
    short8 a[3], bb[8];
#pragma unroll
    for (int c = 0; c < 3; ++c) a[c] = *(const short8*)&Al[cur][aoff[c]];
#pragma unroll
    for (int k = 0; k < 8; ++k) bb[k] = *(const short8*)&Bl[cur][boff[k]];
    __builtin_amdgcn_s_setprio(1);
#pragma unroll
    for (int c = 0; c < 3; ++c)
#pragma unroll
      for (int k = 0; k < 8; ++k)
        acc[c][k] = __builtin_amdgcn_mfma_f32_16x16x32_bf16(
            __builtin_bit_cast(bf16x8, a[c]), __builtin_bit_cast(bf16x8, bb[k]),
            acc[c][k], 0, 0, 0);
    __builtin_amdgcn_s_setprio(0);
    __syncthreads();  // drains this step's async loads (overlapped with the MFMAs above)
    cur ^= 1;
  }

  // epilogue: + bias, * valid, store. D layout: row(co)=quad*4+r, col(p)=l16.
  float bv[3][4];
#pragma unroll
  for (int c = 0; c < 3; ++c)
#pragma unroll
    for (int r = 0; r < 4; ++r) bv[c][r] = bias[wave * 48 + c * 16 + quad * 4 + r];

  const float* vrow = Vg + ((size_t)b * 256 + oh) * 256 + ow0;
  float* ob = out + (size_t)(b * 192) * 65536 + (size_t)oh * 256 + ow0;
#pragma unroll
  for (int s = 0; s < 8; ++s) {
    float v = vrow[s * 16 + l16];
#pragma unroll
    for (int c = 0; c < 3; ++c) {
      int cobase = wave * 48 + c * 16 + quad * 4;
#pragma unroll
      for (int r = 0; r < 4; ++r)
        ob[(size_t)(cobase + r) * 65536 + s * 16 + l16] = (acc[c][s][r] + bv[c][r]) * v;
    }
  }
}

// ---------------- fallback (only if ws too small): direct fp32 conv ----------------
__global__ __launch_bounds__(256) void naive_conv(
    const float* __restrict__ x, const int* __restrict__ mask,
    const float* __restrict__ w, const float* __restrict__ bias,
    float* __restrict__ out) {
  size_t gid = (size_t)blockIdx.x * 256 + threadIdx.x;
  int ow = (int)(gid & 255);
  int oh = (int)((gid >> 8) & 255);
  int rest = (int)(gid >> 16);
  int co = rest % 192;
  int b = rest / 192;
  int any = 0;
  for (int dh = -1; dh <= 1; ++dh) {
    int h = oh + dh;
    if ((unsigned)h >= 256u) continue;
    for (int dw = -1; dw <= 1; ++dw) {
      int ww2 = ow + dw;
      if ((unsigned)ww2 >= 256u) continue;
      any |= (mask[((size_t)b << 16) + h * 256 + ww2] != 0);
    }
  }
  if (!any) { out[gid] = 0.f; return; }
  float acc = bias[co];
  const float* xb = x + (size_t)b * 192 * 65536;
  const float* wc = w + (size_t)co * 192 * 9;
  for (int ci = 0; ci < 192; ++ci) {
    const float* xc = xb + (size_t)ci * 65536;
    const float* wk = wc + ci * 9;
    for (int kh = 0; kh < 3; ++kh) {
      int h = oh + kh - 1;
      if ((unsigned)h >= 256u) continue;
      for (int kw = 0; kw < 3; ++kw) {
        int w2 = ow + kw - 1;
        if ((unsigned)w2 >= 256u) continue;
        acc += xc[h * 256 + w2] * wk[kh * 3 + kw];
      }
    }
  }
  out[gid] = acc;
}

extern "C" void kernel_launch(void* const* d_in, const int* in_sizes, int n_in,
                              void* d_out, int out_size, void* d_ws, size_t ws_size,
                              hipStream_t stream) {
  const float* x = (const float*)d_in[0];
  const int* mask = (const int*)d_in[1];
  const float* w = (const float*)d_in[2];
  const float* bias = (const float*)d_in[3];
  float* out = (float*)d_out;

  const size_t xp_bytes = (size_t)4 * HP * HP * 192 * 2;  // 102,242,304
  const size_t wr_bytes = (size_t)9 * 6 * 768 * 8 * 2;    //     663,552
  const size_t vg_bytes = (size_t)4 * 256 * 256 * 4;      //   1,048,576

  if (d_ws && ws_size >= xp_bytes + wr_bytes + vg_bytes) {
    short* Xp = (short*)d_ws;
    short* Wr = (short*)((char*)d_ws + xp_bytes);
    float* Vg = (float*)((char*)d_ws + xp_bytes + wr_bytes);
    prepass<<<5668, 256, 0, stream>>>(x, mask, w, Xp, Wr, Vg);
    conv_mfma<<<dim3(2, 256, 4), 256, 0, stream>>>(Xp, Wr, Vg, bias, out);
  } else {
    naive_conv<<<196608, 256, 0, stream>>>(x, mask, w, bias, out);
  }
}

// Round 2
// 541.409 us; speedup vs baseline: 1.0967x; 1.0967x over previous
//
#include <hip/hip_runtime.h>

typedef short short8 __attribute__((ext_vector_type(8)));
typedef __bf16 bf16x8 __attribute__((ext_vector_type(8)));
typedef float f32x4 __attribute__((ext_vector_type(4)));

#define HP 258  // padded spatial dim

__device__ __forceinline__ short f2bf(float f) {
  // round-to-nearest-even fp32 -> bf16 (inputs are finite)
  unsigned u = __builtin_bit_cast(unsigned, f);
  unsigned r = u + 0x7fffu + ((u >> 16) & 1u);
  return (short)(r >> 16);
}

__device__ __forceinline__ void async16(void* l, const void* g) {
  __builtin_amdgcn_global_load_lds((const __attribute__((address_space(1))) void*)g,
                                   (__attribute__((address_space(3))) void*)l,
                                   16, 0, 0);
}

// ---------------- fused prepass: all four independent prep jobs in ONE launch ---
// blocks [0,4096): transpose_x   (NCHW fp32 -> padded NHWC bf16)
// blocks [4096,4482): zero_border
// blocks [4482,4644): repack_w
// blocks [4644,5668): valid_mask
__global__ __launch_bounds__(256) void prepass(const float* __restrict__ x,
                                               const int* __restrict__ mask,
                                               const float* __restrict__ Wsrc,
                                               short* __restrict__ Xp,
                                               short* __restrict__ Wr,
                                               float* __restrict__ Vg) {
  __shared__ short lds[64 * 200];  // used by transpose blocks only
  const int t = threadIdx.x;
  const int bid = blockIdx.x;

  if (bid < 4096) {
    // ---- transpose_x: 64-w tile of one (b, ih) row ----
    const int w = t & 63;
    const int g = t >> 6;
    const int w0 = (bid & 3) << 6;
    const int ih = (bid >> 2) & 255;
    const int b = bid >> 10;
    const float* xb = x + ((size_t)b * 192) * 65536 + (size_t)ih * 256 + w0;
#pragma unroll
    for (int pass = 0; pass < 6; ++pass) {
      int ci = pass * 32 + g * 8;
      short8 v;
#pragma unroll
      for (int j = 0; j < 8; ++j) v[j] = f2bf(xb[(size_t)(ci + j) * 65536 + w]);
      *(short8*)&lds[w * 200 + ci] = v;
    }
    __syncthreads();
    short* dst = Xp + (((size_t)b * HP + (ih + 1)) * HP + (w0 + 1)) * 192;
#pragma unroll
    for (int i = 0; i < 6; ++i) {
      int gid = i * 256 + t;  // 1536 granules = 64 w * 24
      int ww = gid / 24;
      int c = gid - ww * 24;
      short8 vv = *(const short8*)&lds[ww * 200 + c * 8];
      *(short8*)&dst[(size_t)ww * 192 + c * 8] = vv;
    }
    return;
  }

  int rb = bid - 4096;
  if (rb < 386) {
    // ---- zero_border ----
    int gid = rb * 256 + t;
    if (gid >= 4 * 1028 * 24) return;
    int g = gid % 24;
    int pix = gid / 24;
    int b = pix / 1028;
    int i = pix - b * 1028;
    int h, w;
    if (i < 258)      { h = 0;   w = i; }
    else if (i < 516) { h = 257; w = i - 258; }
    else { int j = i - 516; h = 1 + (j >> 1); w = (j & 1) ? 257 : 0; }
    short8 z = {0, 0, 0, 0, 0, 0, 0, 0};
    *(short8*)&Xp[(((size_t)b * HP + h) * HP + w) * 192 + g * 8] = z;
    return;
  }
  rb -= 386;
  if (rb < 162) {
    // ---- repack_w: OIHW fp32 -> [tap][kc][swizzled granule] bf16 ----
    int gid = rb * 256 + t;
    if (gid >= 9 * 6 * 768) return;
    int gr = gid % 768;
    int tk = gid / 768;
    int kc = tk % 6;
    int tap = tk / 6;
    int co = gr >> 2;
    int q = (gr & 3) ^ (co & 3);  // XOR swizzle so frag ds_read_b128 is conflict-free
    int ci = kc * 32 + q * 8;
    short8 v;
#pragma unroll
    for (int j = 0; j < 8; ++j) v[j] = f2bf(Wsrc[(size_t)(co * 192 + ci + j) * 9 + tap]);
    *(short8*)&Wr[(size_t)gid * 8] = v;
    return;
  }
  rb -= 162;
  {
    // ---- valid_mask = any(mask 3x3 window) ----
    int gid = rb * 256 + t;  // 262144 exact
    int b = gid >> 16;
    int r = gid & 65535;
    int oh = r >> 8;
    int ow = r & 255;
    const int* mb = mask + ((size_t)b << 16);
    int any = 0;
    for (int dh = -1; dh <= 1; ++dh) {
      int h = oh + dh;
      if ((unsigned)h >= 256u) continue;
      for (int dw = -1; dw <= 1; ++dw) {
        int w = ow + dw;
        if ((unsigned)w >= 256u) continue;
        any |= (mb[h * 256 + w] != 0);
      }
    }
    Vg[gid] = any ? 1.0f : 0.0f;
  }
}

// ---------------- main: implicit-GEMM conv, bf16 MFMA 16x16x32 ----------------
// WG tile: 192 cout x 128 ow (one output row segment). 4 waves: wave w -> cout [48w,48w+48).
// 2-phase pipeline, FULLY UNROLLED 54-step K-loop: buffer index (s&1), tap/kc
// decode, LDS offsets and staging offsets all constant-fold. One barrier per
// step; its implicit vmcnt(0) drain lands AFTER the MFMA cluster so the async
// global->LDS latency hides under compute.
__global__ __launch_bounds__(256) void conv_mfma(
    const short* __restrict__ Xp,   // [4][258][258][192] bf16 padded NHWC
    const short* __restrict__ Wr,   // [9][6][768 granules][8] bf16 swizzled (linear in step)
    const float* __restrict__ Vg,   // [4][256][256]
    const float* __restrict__ bias, // [192]
    float* __restrict__ out)        // [4][192][256][256]
{
  __shared__ short Al[2][768 * 8];  // 2 x 12 KB: A chunk, 192 co x 32 ci
  __shared__ short Bl[2][512 * 8];  // 2 x 8 KB:  B chunk, 128 p x 32 ci

  const int t = threadIdx.x;
  const int lane = t & 63;
  const int wave = t >> 6;
  const int quad = lane >> 4;
  const int l16 = lane & 15;

  const int b = blockIdx.z;
  const int by = blockIdx.y;
  // XCD banding (kept: FETCH_SIZE 210->68 MB): by%4 selects a 64-row oh band;
  // consecutive rows within a band land on the same XCD pair's L2.
  const int oh = ((by & 3) << 6) | (by >> 2);
  const int ow0 = blockIdx.x << 7;

  // LDS frag read offsets (shorts), loop-invariant. XOR matches staging swizzle.
  const int axor = quad ^ (l16 & 3);
  int aoff[3];
#pragma unroll
  for (int c = 0; c < 3; ++c) aoff[c] = ((wave * 48 + c * 16 + l16) * 4 + axor) * 8;
  int boff[8];
#pragma unroll
  for (int s = 0; s < 8; ++s) boff[s] = ((s * 16 + l16) * 4 + axor) * 8;

  // B staging decode: thread t copies granules t and t+256 (pixels p0 and p0+64).
  const int p0 = t >> 2;
  const int q0 = (t & 3) ^ (p0 & 3);
  const int poff = p0 * 192 + q0 * 8;

  const f32x4 fzero = {0.f, 0.f, 0.f, 0.f};
  f32x4 acc[3][8];
#pragma unroll
  for (int c = 0; c < 3; ++c)
#pragma unroll
    for (int s = 0; s < 8; ++s) acc[c][s] = fzero;

  // Per-lane bases; all per-step offsets below are compile-time constants.
  const short* wbase = Wr + (size_t)t * 8;
  const short* xbase = Xp + (size_t)b * HP * HP * 192 + ((size_t)oh * HP + ow0) * 192 + poff;

  // prologue: fill buffer 0 with step 0 (tap(0,0), kc 0)
  async16(&Al[0][t * 8], wbase);
  async16(&Al[0][(t + 256) * 8], wbase + 256 * 8);
  async16(&Al[0][(t + 512) * 8], wbase + 512 * 8);
  async16(&Bl[0][t * 8], xbase);
  async16(&Bl[0][(t + 256) * 8], xbase + 64 * 192);
  __syncthreads();  // vmcnt(0) drain + barrier

#pragma unroll
  for (int s = 0; s < 54; ++s) {  // step = tap*6 + kc; fully unrolled -> all static
    const int cb = s & 1;
    const int sn = s + 1;
    if (sn < 54) {  // issue next step's loads into the other buffer FIRST
      const int tap = sn / 6;
      const int kc = sn - tap * 6;
      const int kh = tap / 3;
      const int kw = tap - kh * 3;
      const short* wsrc = wbase + (size_t)sn * (768 * 8);  // Wr linear in step
      async16(&Al[cb ^ 1][t * 8], wsrc);
      async16(&Al[cb ^ 1][(t + 256) * 8], wsrc + 256 * 8);
      async16(&Al[cb ^ 1][(t + 512) * 8], wsrc + 512 * 8);
      const short* xsrc = xbase + ((size_t)kh * HP + kw) * 192 + kc * 32;
      async16(&Bl[cb ^ 1][t * 8], xsrc);
      async16(&Bl[cb ^ 1][(t + 256) * 8], xsrc + 64 * 192);
    }
    short8 a[3], bb[8];
#pragma unroll
    for (int c = 0; c < 3; ++c) a[c] = *(const short8*)&Al[cb][aoff[c]];
#pragma unroll
    for (int k = 0; k < 8; ++k) bb[k] = *(const short8*)&Bl[cb][boff[k]];
    __builtin_amdgcn_s_setprio(1);
#pragma unroll
    for (int c = 0; c < 3; ++c)
#pragma unroll
      for (int k = 0; k < 8; ++k)
        acc[c][k] = __builtin_amdgcn_mfma_f32_16x16x32_bf16(
            __builtin_bit_cast(bf16x8, a[c]), __builtin_bit_cast(bf16x8, bb[k]),
            acc[c][k], 0, 0, 0);
    __builtin_amdgcn_s_setprio(0);
    __syncthreads();  // drains this step's async loads (overlapped with the MFMAs above)
  }

  // epilogue: + bias, * valid, store. D layout: row(co)=quad*4+r, col(p)=l16.
  float bv[3][4];
#pragma unroll
  for (int c = 0; c < 3; ++c)
#pragma unroll
    for (int r = 0; r < 4; ++r) bv[c][r] = bias[wave * 48 + c * 16 + quad * 4 + r];

  const float* vrow = Vg + ((size_t)b * 256 + oh) * 256 + ow0;
  float* ob = out + (size_t)(b * 192) * 65536 + (size_t)oh * 256 + ow0;
#pragma unroll
  for (int s = 0; s < 8; ++s) {
    float v = vrow[s * 16 + l16];
#pragma unroll
    for (int c = 0; c < 3; ++c) {
      int cobase = wave * 48 + c * 16 + quad * 4;
#pragma unroll
      for (int r = 0; r < 4; ++r)
        ob[(size_t)(cobase + r) * 65536 + s * 16 + l16] = (acc[c][s][r] + bv[c][r]) * v;
    }
  }
}

// ---------------- fallback (only if ws too small): direct fp32 conv ----------------
__global__ __launch_bounds__(256) void naive_conv(
    const float* __restrict__ x, const int* __restrict__ mask,
    const float* __restrict__ w, const float* __restrict__ bias,
    float* __restrict__ out) {
  size_t gid = (size_t)blockIdx.x * 256 + threadIdx.x;
  int ow = (int)(gid & 255);
  int oh = (int)((gid >> 8) & 255);
  int rest = (int)(gid >> 16);
  int co = rest % 192;
  int b = rest / 192;
  int any = 0;
  for (int dh = -1; dh <= 1; ++dh) {
    int h = oh + dh;
    if ((unsigned)h >= 256u) continue;
    for (int dw = -1; dw <= 1; ++dw) {
      int ww2 = ow + dw;
      if ((unsigned)ww2 >= 256u) continue;
      any |= (mask[((size_t)b << 16) + h * 256 + ww2] != 0);
    }
  }
  if (!any) { out[gid] = 0.f; return; }
  float acc = bias[co];
  const float* xb = x + (size_t)b * 192 * 65536;
  const float* wc = w + (size_t)co * 192 * 9;
  for (int ci = 0; ci < 192; ++ci) {
    const float* xc = xb + (size_t)ci * 65536;
    const float* wk = wc + ci * 9;
    for (int kh = 0; kh < 3; ++kh) {
      int h = oh + kh - 1;
      if ((unsigned)h >= 256u) continue;
      for (int kw = 0; kw < 3; ++kw) {
        int w2 = ow + kw - 1;
        if ((unsigned)w2 >= 256u) continue;
        acc += xc[h * 256 + w2] * wk[kh * 3 + kw];
      }
    }
  }
  out[gid] = acc;
}

extern "C" void kernel_launch(void* const* d_in, const int* in_sizes, int n_in,
                              void* d_out, int out_size, void* d_ws, size_t ws_size,
                              hipStream_t stream) {
  const float* x = (const float*)d_in[0];
  const int* mask = (const int*)d_in[1];
  const float* w = (const float*)d_in[2];
  const float* bias = (const float*)d_in[3];
  float* out = (float*)d_out;

  const size_t xp_bytes = (size_t)4 * HP * HP * 192 * 2;  // 102,242,304
  const size_t wr_bytes = (size_t)9 * 6 * 768 * 8 * 2;    //     663,552
  const size_t vg_bytes = (size_t)4 * 256 * 256 * 4;      //   1,048,576

  if (d_ws && ws_size >= xp_bytes + wr_bytes + vg_bytes) {
    short* Xp = (short*)d_ws;
    short* Wr = (short*)((char*)d_ws + xp_bytes);
    float* Vg = (float*)((char*)d_ws + xp_bytes + wr_bytes);
    prepass<<<5668, 256, 0, stream>>>(x, mask, w, Xp, Wr, Vg);
    conv_mfma<<<dim3(2, 256, 4), 256, 0, stream>>>(Xp, Wr, Vg, bias, out);
  } else {
    naive_conv<<<196608, 256, 0, stream>>>(x, mask, w, bias, out);
  }
}

// Round 3
// 494.392 us; speedup vs baseline: 1.2009x; 1.0951x over previous
//
#include <hip/hip_runtime.h>

typedef short short8 __attribute__((ext_vector_type(8)));
typedef __bf16 bf16x8 __attribute__((ext_vector_type(8)));
typedef float f32x4 __attribute__((ext_vector_type(4)));

#define HP 258  // padded spatial dim

__device__ __forceinline__ short f2bf(float f) {
  // round-to-nearest-even fp32 -> bf16 (inputs are finite)
  unsigned u = __builtin_bit_cast(unsigned, f);
  unsigned r = u + 0x7fffu + ((u >> 16) & 1u);
  return (short)(r >> 16);
}

__device__ __forceinline__ void async16(void* l, const void* g) {
  __builtin_amdgcn_global_load_lds((const __attribute__((address_space(1))) void*)g,
                                   (__attribute__((address_space(3))) void*)l,
                                   16, 0, 0);
}

// ---------------- fused prepass: all four independent prep jobs in ONE launch ---
// blocks [0,4096): transpose_x   (NCHW fp32 -> padded NHWC bf16)
// blocks [4096,4482): zero_border
// blocks [4482,4644): repack_w
// blocks [4644,5668): valid_mask
__global__ __launch_bounds__(256) void prepass(const float* __restrict__ x,
                                               const int* __restrict__ mask,
                                               const float* __restrict__ Wsrc,
                                               short* __restrict__ Xp,
                                               short* __restrict__ Wr,
                                               float* __restrict__ Vg) {
  __shared__ short lds[64 * 200];  // used by transpose blocks only
  const int t = threadIdx.x;
  const int bid = blockIdx.x;

  if (bid < 4096) {
    // ---- transpose_x: 64-w tile of one (b, ih) row ----
    const int w = t & 63;
    const int g = t >> 6;
    const int w0 = (bid & 3) << 6;
    const int ih = (bid >> 2) & 255;
    const int b = bid >> 10;
    const float* xb = x + ((size_t)b * 192) * 65536 + (size_t)ih * 256 + w0;
#pragma unroll
    for (int pass = 0; pass < 6; ++pass) {
      int ci = pass * 32 + g * 8;
      short8 v;
#pragma unroll
      for (int j = 0; j < 8; ++j) v[j] = f2bf(xb[(size_t)(ci + j) * 65536 + w]);
      *(short8*)&lds[w * 200 + ci] = v;
    }
    __syncthreads();
    short* dst = Xp + (((size_t)b * HP + (ih + 1)) * HP + (w0 + 1)) * 192;
#pragma unroll
    for (int i = 0; i < 6; ++i) {
      int gid = i * 256 + t;  // 1536 granules = 64 w * 24
      int ww = gid / 24;
      int c = gid - ww * 24;
      short8 vv = *(const short8*)&lds[ww * 200 + c * 8];
      *(short8*)&dst[(size_t)ww * 192 + c * 8] = vv;
    }
    return;
  }

  int rb = bid - 4096;
  if (rb < 386) {
    // ---- zero_border ----
    int gid = rb * 256 + t;
    if (gid >= 4 * 1028 * 24) return;
    int g = gid % 24;
    int pix = gid / 24;
    int b = pix / 1028;
    int i = pix - b * 1028;
    int h, w;
    if (i < 258)      { h = 0;   w = i; }
    else if (i < 516) { h = 257; w = i - 258; }
    else { int j = i - 516; h = 1 + (j >> 1); w = (j & 1) ? 257 : 0; }
    short8 z = {0, 0, 0, 0, 0, 0, 0, 0};
    *(short8*)&Xp[(((size_t)b * HP + h) * HP + w) * 192 + g * 8] = z;
    return;
  }
  rb -= 386;
  if (rb < 162) {
    // ---- repack_w: OIHW fp32 -> [tap][kc][swizzled granule] bf16 ----
    // Layout: slot (gr&3) of row co holds granule q = slot ^ ((co>>1)&3).
    // (l16>>1 XOR: makes each 8-lane b128 group cover all 8 bank quartets.)
    int gid = rb * 256 + t;
    if (gid >= 9 * 6 * 768) return;
    int gr = gid % 768;
    int tk = gid / 768;
    int kc = tk % 6;
    int tap = tk / 6;
    int co = gr >> 2;
    int q = (gr & 3) ^ ((co >> 1) & 3);  // conflict-free XOR swizzle
    int ci = kc * 32 + q * 8;
    short8 v;
#pragma unroll
    for (int j = 0; j < 8; ++j) v[j] = f2bf(Wsrc[(size_t)(co * 192 + ci + j) * 9 + tap]);
    *(short8*)&Wr[(size_t)gid * 8] = v;
    return;
  }
  rb -= 162;
  {
    // ---- valid_mask = any(mask 3x3 window) ----
    int gid = rb * 256 + t;  // 262144 exact
    int b = gid >> 16;
    int r = gid & 65535;
    int oh = r >> 8;
    int ow = r & 255;
    const int* mb = mask + ((size_t)b << 16);
    int any = 0;
    for (int dh = -1; dh <= 1; ++dh) {
      int h = oh + dh;
      if ((unsigned)h >= 256u) continue;
      for (int dw = -1; dw <= 1; ++dw) {
        int w = ow + dw;
        if ((unsigned)w >= 256u) continue;
        any |= (mb[h * 256 + w] != 0);
      }
    }
    Vg[gid] = any ? 1.0f : 0.0f;
  }
}

// ---------------- main: implicit-GEMM conv, bf16 MFMA 16x16x32 ----------------
// WG tile: 192 cout x 128 ow. 4 waves: wave w -> cout [48w,48w+48).
// BK=64: each step stages TWO 32-ci chunks (27 steps, 48 MFMA/step) so the
// async global->LDS latency (~500-900 cyc) hides under a ~940-cyc compute
// window. Double-buffered 80 KB LDS (2 blocks/CU — same as the VGPR limit).
// LDS slot swizzle quad^((l16>>1)&3) makes every ds_read_b128 8-lane group
// hit all 32 banks (fixes the measured +4 cyc/read conflict).
__global__ __launch_bounds__(256) void conv_mfma(
    const short* __restrict__ Xp,   // [4][258][258][192] bf16 padded NHWC
    const short* __restrict__ Wr,   // [9][6][768 granules][8] bf16 swizzled (linear in kc-chunk)
    const float* __restrict__ Vg,   // [4][256][256]
    const float* __restrict__ bias, // [192]
    float* __restrict__ out)        // [4][192][256][256]
{
  __shared__ short Al[2][2][768 * 8];  // [buf][kc-half]: 4 x 12 KB, 192 co x 32 ci each
  __shared__ short Bl[2][2][512 * 8];  // [buf][kc-half]: 4 x 8 KB,  128 p x 32 ci each

  const int t = threadIdx.x;
  const int lane = t & 63;
  const int wave = t >> 6;
  const int quad = lane >> 4;
  const int l16 = lane & 15;

  const int b = blockIdx.z;
  const int by = blockIdx.y;
  // XCD banding (kept: FETCH_SIZE 210->68 MB): by%4 selects a 64-row oh band.
  const int oh = ((by & 3) << 6) | (by >> 2);
  const int ow0 = blockIdx.x << 7;

  // LDS frag read offsets (shorts), loop-invariant. XOR matches staging swizzle.
  const int axor = quad ^ ((l16 >> 1) & 3);
  int aoff[3];
#pragma unroll
  for (int c = 0; c < 3; ++c) aoff[c] = ((wave * 48 + c * 16 + l16) * 4 + axor) * 8;
  int boff[8];
#pragma unroll
  for (int s = 0; s < 8; ++s) boff[s] = ((s * 16 + l16) * 4 + axor) * 8;

  // B staging decode: thread t stages slot (t&3) of pixel p0=t>>2, which holds
  // data granule q0 = (t&3) ^ ((p0>>1)&3).
  const int p0 = t >> 2;
  const int q0 = (t & 3) ^ ((p0 >> 1) & 3);
  const int poff = p0 * 192 + q0 * 8;

  const f32x4 fzero = {0.f, 0.f, 0.f, 0.f};
  f32x4 acc[3][8];
#pragma unroll
  for (int c = 0; c < 3; ++c)
#pragma unroll
    for (int s = 0; s < 8; ++s) acc[c][s] = fzero;

  // Per-lane bases; all per-step offsets below are compile-time constants.
  const short* wbase = Wr + (size_t)t * 8;
  const short* xbase = Xp + (size_t)b * HP * HP * 192 + ((size_t)oh * HP + ow0) * 192 + poff;

  auto stageA = [&](int buf, const short* wsrc) {  // buf is constant after unroll
    async16(&Al[buf][0][t * 8], wsrc);
    async16(&Al[buf][0][(t + 256) * 8], wsrc + 2048);
    async16(&Al[buf][0][(t + 512) * 8], wsrc + 4096);
    async16(&Al[buf][1][t * 8], wsrc + 6144);
    async16(&Al[buf][1][(t + 256) * 8], wsrc + 6144 + 2048);
    async16(&Al[buf][1][(t + 512) * 8], wsrc + 6144 + 4096);
  };
  auto stageB = [&](int buf, const short* xsrc) {
    async16(&Bl[buf][0][t * 8], xsrc);
    async16(&Bl[buf][0][(t + 256) * 8], xsrc + 64 * 192);
    async16(&Bl[buf][1][t * 8], xsrc + 32);
    async16(&Bl[buf][1][(t + 256) * 8], xsrc + 64 * 192 + 32);
  };

  // prologue: fill buffer 0 with step 0 (tap(0,0), kc pair 0 -> ci 0..63)
  stageA(0, wbase);
  stageB(0, xbase);
  __syncthreads();  // vmcnt(0) drain + barrier

#pragma unroll
  for (int s = 0; s < 27; ++s) {  // step = tap*3 + kcpair; fully unrolled -> all static
    const int cb = s & 1;
    const int sn = s + 1;
    if (sn < 27) {  // issue next step's 10 loads into the other buffer FIRST
      const int tap = sn / 3;
      const int kcp = sn - tap * 3;
      const int kh = tap / 3;
      const int kw = tap - kh * 3;
      stageA(cb ^ 1, wbase + (size_t)(tap * 6 + kcp * 2) * 6144);  // Wr linear in kc-chunk
      stageB(cb ^ 1, xbase + ((size_t)kh * HP + kw) * 192 + kcp * 64);
    }
#pragma unroll
    for (int h = 0; h < 2; ++h) {  // two 32-ci halves; same kc order as before
      short8 a[3], bb[8];
#pragma unroll
      for (int c = 0; c < 3; ++c) a[c] = *(const short8*)&Al[cb][h][aoff[c]];
#pragma unroll
      for (int k = 0; k < 8; ++k) bb[k] = *(const short8*)&Bl[cb][h][boff[k]];
      __builtin_amdgcn_s_setprio(1);
#pragma unroll
      for (int c = 0; c < 3; ++c)
#pragma unroll
        for (int k = 0; k < 8; ++k)
          acc[c][k] = __builtin_amdgcn_mfma_f32_16x16x32_bf16(
              __builtin_bit_cast(bf16x8, a[c]), __builtin_bit_cast(bf16x8, bb[k]),
              acc[c][k], 0, 0, 0);
      __builtin_amdgcn_s_setprio(0);
    }
    __syncthreads();  // drains this step's async loads (overlapped with 48 MFMAs above)
  }

  // epilogue: + bias, * valid, store. D layout: row(co)=quad*4+r, col(p)=l16.
  float bv[3][4];
#pragma unroll
  for (int c = 0; c < 3; ++c)
#pragma unroll
    for (int r = 0; r < 4; ++r) bv[c][r] = bias[wave * 48 + c * 16 + quad * 4 + r];

  const float* vrow = Vg + ((size_t)b * 256 + oh) * 256 + ow0;
  float* ob = out + (size_t)(b * 192) * 65536 + (size_t)oh * 256 + ow0;
#pragma unroll
  for (int s = 0; s < 8; ++s) {
    float v = vrow[s * 16 + l16];
#pragma unroll
    for (int c = 0; c < 3; ++c) {
      int cobase = wave * 48 + c * 16 + quad * 4;
#pragma unroll
      for (int r = 0; r < 4; ++r)
        ob[(size_t)(cobase + r) * 65536 + s * 16 + l16] = (acc[c][s][r] + bv[c][r]) * v;
    }
  }
}

// ---------------- fallback (only if ws too small): direct fp32 conv ----------------
__global__ __launch_bounds__(256) void naive_conv(
    const float* __restrict__ x, const int* __restrict__ mask,
    const float* __restrict__ w, const float* __restrict__ bias,
    float* __restrict__ out) {
  size_t gid = (size_t)blockIdx.x * 256 + threadIdx.x;
  int ow = (int)(gid & 255);
  int oh = (int)((gid >> 8) & 255);
  int rest = (int)(gid >> 16);
  int co = rest % 192;
  int b = rest / 192;
  int any = 0;
  for (int dh = -1; dh <= 1; ++dh) {
    int h = oh + dh;
    if ((unsigned)h >= 256u) continue;
    for (int dw = -1; dw <= 1; ++dw) {
      int ww2 = ow + dw;
      if ((unsigned)ww2 >= 256u) continue;
      any |= (mask[((size_t)b << 16) + h * 256 + ww2] != 0);
    }
  }
  if (!any) { out[gid] = 0.f; return; }
  float acc = bias[co];
  const float* xb = x + (size_t)b * 192 * 65536;
  const float* wc = w + (size_t)co * 192 * 9;
  for (int ci = 0; ci < 192; ++ci) {
    const float* xc = xb + (size_t)ci * 65536;
    const float* wk = wc + ci * 9;
    for (int kh = 0; kh < 3; ++kh) {
      int h = oh + kh - 1;
      if ((unsigned)h >= 256u) continue;
      for (int kw = 0; kw < 3; ++kw) {
        int w2 = ow + kw - 1;
        if ((unsigned)w2 >= 256u) continue;
        acc += xc[h * 256 + w2] * wk[kh * 3 + kw];
      }
    }
  }
  out[gid] = acc;
}

extern "C" void kernel_launch(void* const* d_in, const int* in_sizes, int n_in,
                              void* d_out, int out_size, void* d_ws, size_t ws_size,
                              hipStream_t stream) {
  const float* x = (const float*)d_in[0];
  const int* mask = (const int*)d_in[1];
  const float* w = (const float*)d_in[2];
  const float* bias = (const float*)d_in[3];
  float* out = (float*)d_out;

  const size_t xp_bytes = (size_t)4 * HP * HP * 192 * 2;  // 102,242,304
  const size_t wr_bytes = (size_t)9 * 6 * 768 * 8 * 2;    //     663,552
  const size_t vg_bytes = (size_t)4 * 256 * 256 * 4;      //   1,048,576

  if (d_ws && ws_size >= xp_bytes + wr_bytes + vg_bytes) {
    short* Xp = (short*)d_ws;
    short* Wr = (short*)((char*)d_ws + xp_bytes);
    float* Vg = (float*)((char*)d_ws + xp_bytes + wr_bytes);
    prepass<<<5668, 256, 0, stream>>>(x, mask, w, Xp, Wr, Vg);
    conv_mfma<<<dim3(2, 256, 4), 256, 0, stream>>>(Xp, Wr, Vg, bias, out);
  } else {
    naive_conv<<<196608, 256, 0, stream>>>(x, mask, w, bias, out);
  }
}